// Round 12
// baseline (617.801 us; speedup 1.0000x reference)
//
#include <hip/hip_runtime.h>
#include <hip/hip_bf16.h>

#define N_NODES 50000
#define N_PAD 50064            // N rounded up to 64 for tail-safe A-frag loads
#define N_EDGES 800000
#define EMB_D 128
#define HID_D 256
#define OUT_D 128
#define NGRAPH 256

#define SCAN_B ((N_NODES + 256) / 256)
#define NSHARD 8

typedef __attribute__((ext_vector_type(8))) short short8;
typedef __attribute__((ext_vector_type(4))) float floatx4;
typedef __attribute__((ext_vector_type(2))) float floatx2;
typedef __attribute__((ext_vector_type(2))) unsigned short ushortx2;
typedef __attribute__((ext_vector_type(4))) unsigned short ushortx4;

__device__ inline void bf16split(float x, short& hi, short& lo) {
    __hip_bfloat16 h = __float2bfloat16(x);
    float r = x - __bfloat162float(h);
    __hip_bfloat16 l = __float2bfloat16(r);
    hi = *reinterpret_cast<short*>(&h);
    lo = *reinterpret_cast<short*>(&l);
}

__device__ inline unsigned short f2b(float f) {
    __hip_bfloat16 h = __float2bfloat16(f);
    return *reinterpret_cast<unsigned short*>(&h);
}

__device__ inline float b2f(unsigned short u) {
    union { unsigned int i; float f; } c;
    c.i = ((unsigned int)u) << 16;
    return c.f;
}

template<int VPL> struct UVec;
template<> struct UVec<2> { using T = ushortx2; using FV = floatx2; };
template<> struct UVec<4> { using T = ushortx4; using FV = floatx4; };

// ---------------- rank pass: 8-shard degree histogram + per-edge rank ----------------
__global__ void rank_kernel(const int* __restrict__ dst, int* __restrict__ deg8,
                            int* __restrict__ pos) {
    int e = blockIdx.x * blockDim.x + threadIdx.x;
    if (e >= N_EDGES) return;
    pos[e] = atomicAdd(&deg8[(size_t)(e & (NSHARD - 1)) * N_NODES + dst[e]], 1);
}

// ---------------- graph boundaries via binary search (batch is sorted) ----------------
__global__ void bstart_kernel(const int* __restrict__ batch, int* __restrict__ bstart) {
    int g = threadIdx.x;
    if (g > NGRAPH) return;
    int lo = 0, hi = N_NODES;
    while (lo < hi) {
        int mid = (lo + hi) >> 1;
        if (batch[mid] < g) lo = mid + 1;
        else hi = mid;
    }
    bstart[g] = lo;
}

// ---------------- scan phase A ----------------
__global__ void scan_a(const int* __restrict__ deg8, int* __restrict__ degt,
                       int* __restrict__ sb8, int* __restrict__ bsum,
                       float* __restrict__ dinv) {
    __shared__ int red[256];
    int t = threadIdx.x;
    int i = blockIdx.x * 256 + t;
    int tot = 0;
    if (i < N_NODES) {
        int run = 0;
#pragma unroll
        for (int k = 0; k < NSHARD; ++k) {
            sb8[(size_t)k * N_NODES + i] = run;
            run += deg8[(size_t)k * N_NODES + i];
        }
        tot = run;
        degt[i] = tot;
        dinv[i] = rsqrtf((float)tot + 1.0f);
    }
    red[t] = tot;
    __syncthreads();
    for (int off = 128; off > 0; off >>= 1) {
        if (t < off) red[t] += red[t + off];
        __syncthreads();
    }
    if (t == 0) bsum[blockIdx.x] = red[0];
}

// ---------------- phase B ----------------
__global__ void scan_b(const int* __restrict__ bsum, int* __restrict__ boff) {
    __shared__ int s[256];
    int t = threadIdx.x;
    s[t] = (t < SCAN_B) ? bsum[t] : 0;
    __syncthreads();
    for (int off = 1; off < 256; off <<= 1) {
        int v = (t >= off) ? s[t - off] : 0;
        __syncthreads();
        s[t] += v;
        __syncthreads();
    }
    if (t < SCAN_B) boff[t] = (t == 0) ? 0 : s[t - 1];
}

// ---------------- phase C ----------------
__global__ void scan_c(const int* __restrict__ degt, const int* __restrict__ boff,
                       int* __restrict__ row_start) {
    __shared__ int s[256];
    int t = threadIdx.x;
    int i = blockIdx.x * 256 + t;
    int v = (i < N_NODES) ? degt[i] : 0;
    s[t] = v;
    __syncthreads();
    for (int off = 1; off < 256; off <<= 1) {
        int x = (t >= off) ? s[t - off] : 0;
        __syncthreads();
        s[t] += x;
        __syncthreads();
    }
    int excl = s[t] - v;
    int rs = boff[blockIdx.x] + excl;
    if (i <= N_NODES) row_start[i] = rs;
}

// ---------------- atomic-free CSR scatter ----------
__global__ void scatter_kernel(const int* __restrict__ src, const int* __restrict__ dst,
                               const int* __restrict__ pos, const int* __restrict__ row_start,
                               const int* __restrict__ sb8,
                               int* __restrict__ csr_src) {
    int e = blockIdx.x * blockDim.x + threadIdx.x;
    if (e >= N_EDGES) return;
    int d = dst[e];
    int slot = row_start[d] + sb8[(size_t)(e & (NSHARD - 1)) * N_NODES + d] + pos[e];
    csr_src[slot] = src[e];
}

// ---------------- embedding gather -> pre-scaled bf16 rows ----
__global__ void gather_bf16(const int* __restrict__ ids, const float* __restrict__ embed,
                            const float* __restrict__ dinv, unsigned short* __restrict__ X0) {
    int idx = blockIdx.x * blockDim.x + threadIdx.x;
    const int V = EMB_D / 4;
    if (idx >= N_NODES * V) return;
    int row = idx / V, c = idx % V;
    floatx4 v = ((const floatx4*)embed)[(size_t)ids[row] * V + c];
    float s = dinv[row];
    ushortx4 u;
    u[0] = f2b(v[0] * s); u[1] = f2b(v[1] * s); u[2] = f2b(v[2] * s); u[3] = f2b(v[3] * s);
    ((ushortx4*)X0)[idx] = u;
}

// ---------------- fused aggregation over pre-scaled bf16 rows ----------------
// val = dinv[i]*(sum_e H'[src_e] + H'[i]) (+b) (+res from hi/lo planes) (relu)
// OMODE 0: fp32 out to OUTF.  OMODE 2: split bf16 hi/lo planes (GEMM A-input form).
template<int D, bool HASB, bool RES, bool RELU, int OMODE>
__global__ __launch_bounds__(256) void agg_node(
        const int* __restrict__ row_start, const int* __restrict__ csr_src,
        const float* __restrict__ dinv,
        const unsigned short* __restrict__ Hs, const float* __restrict__ b,
        float* __restrict__ OUTF, unsigned short* __restrict__ Ohi,
        unsigned short* __restrict__ Olo) {
    constexpr int VPL = D / 64;
    using UV = typename UVec<VPL>::T;
    using FV = typename UVec<VPL>::FV;
    int wave = threadIdx.x >> 6, lane = threadIdx.x & 63;
    int i = blockIdx.x * 4 + wave;
    if (i >= N_NODES) return;
    const int off = lane * VPL;
    float acc0[VPL], acc1[VPL];
#pragma unroll
    for (int v = 0; v < VPL; ++v) { acc0[v] = 0.f; acc1[v] = 0.f; }
    int e0 = row_start[i], e1 = row_start[i + 1];
    int e = e0;
    for (; e + 3 < e1; e += 4) {
        int s0 = csr_src[e], s1 = csr_src[e + 1], s2 = csr_src[e + 2], s3 = csr_src[e + 3];
        UV u0 = *(const UV*)(Hs + (size_t)s0 * D + off);
        UV u1 = *(const UV*)(Hs + (size_t)s1 * D + off);
        UV u2 = *(const UV*)(Hs + (size_t)s2 * D + off);
        UV u3 = *(const UV*)(Hs + (size_t)s3 * D + off);
#pragma unroll
        for (int v = 0; v < VPL; ++v) acc0[v] += b2f(u0[v]);
#pragma unroll
        for (int v = 0; v < VPL; ++v) acc1[v] += b2f(u1[v]);
#pragma unroll
        for (int v = 0; v < VPL; ++v) acc0[v] += b2f(u2[v]);
#pragma unroll
        for (int v = 0; v < VPL; ++v) acc1[v] += b2f(u3[v]);
    }
    for (; e < e1; ++e) {
        int s0 = csr_src[e];
        UV u0 = *(const UV*)(Hs + (size_t)s0 * D + off);
#pragma unroll
        for (int v = 0; v < VPL; ++v) acc0[v] += b2f(u0[v]);
    }
    UV us = *(const UV*)(Hs + (size_t)i * D + off);
    float di = dinv[i];
    FV res0, res1;
    if (RES) {
        UV rh = *(const UV*)(Ohi + (size_t)i * D + off);
        UV rl = *(const UV*)(Olo + (size_t)i * D + off);
#pragma unroll
        for (int v = 0; v < VPL; ++v) { res0[v] = b2f(rh[v]); res1[v] = b2f(rl[v]); }
    }
    float val[VPL];
#pragma unroll
    for (int v = 0; v < VPL; ++v) {
        float x = (acc0[v] + acc1[v] + b2f(us[v])) * di;
        if (HASB) x += b[off + v];
        if (RES)  x += res0[v] + res1[v];
        if (RELU) x = fmaxf(x, 0.f);
        val[v] = x;
    }
    if (OMODE == 0) {
        FV outv;
#pragma unroll
        for (int v = 0; v < VPL; ++v) outv[v] = val[v];
        *(FV*)(OUTF + (size_t)i * D + off) = outv;
    } else {
        UV hiv, lov;
#pragma unroll
        for (int v = 0; v < VPL; ++v) {
            short h, l;
            bf16split(val[v], h, l);
            hiv[v] = (unsigned short)h;
            lov[v] = (unsigned short)l;
        }
        *(UV*)(Ohi + (size_t)i * D + off) = hiv;
        *(UV*)(Olo + (size_t)i * D + off) = lov;
    }
}

// ---------------- W pre-split into B-fragment-major bf16 hi/lo ----------------
template<int K, int D>
__global__ void wsplit_k(const float* __restrict__ W, short* __restrict__ hi,
                         short* __restrict__ lo) {
    int idx = blockIdx.x * blockDim.x + threadIdx.x;
    if (idx >= K * D) return;
    int j = idx & 7;
    int l = (idx >> 3) & 63;
    int rest = idx >> 9;
    int kb = rest % (K / 32);
    int t = rest / (K / 32);
    int k = kb * 32 + (l >> 4) * 8 + j;
    int ncol = t * 16 + (l & 15);
    bf16split(W[(size_t)k * D + ncol], hi[idx], lo[idx]);
}

// ---------------- LDS-free MFMA GEMM: A pre-split hi/lo row-major planes ----------------
// A-frag for lane(m=lane&15,quad=lane>>4) at k-step kb = 8 consecutive k at row m:
// row-major bf16 IS fragment order. No LDS, no barriers.
// OMODE 1: row-scaled bf16 out (O16). OMODE 2: split hi/lo planes out.
template<int K, int D, bool BIAS, bool RELU, int OMODE, bool SCALE>
__global__ __launch_bounds__(256) void gemm_direct(
        const unsigned short* __restrict__ Ahi, const unsigned short* __restrict__ Alo,
        const short* __restrict__ Whi, const short* __restrict__ Wlo,
        const float* __restrict__ b, const float* __restrict__ sc,
        unsigned short* __restrict__ O16, unsigned short* __restrict__ Ohi,
        unsigned short* __restrict__ Olo, int n) {
    constexpr int NT = D / 64;
    constexpr int KB = K / 32;
    int row0 = blockIdx.x * 64;
    int wave = threadIdx.x >> 6, lane = threadIdx.x & 63;
    int quad = lane >> 4, lane15 = lane & 15;

    floatx4 acc[4][NT];
#pragma unroll
    for (int mt = 0; mt < 4; ++mt)
#pragma unroll
        for (int nt = 0; nt < NT; ++nt)
            acc[mt][nt] = (floatx4){0.f, 0.f, 0.f, 0.f};

#pragma unroll
    for (int kb = 0; kb < KB; ++kb) {
        short8 ah[4], al[4];
#pragma unroll
        for (int mt = 0; mt < 4; ++mt) {
            size_t a = (size_t)(row0 + mt * 16 + lane15) * K + kb * 32 + quad * 8;
            ah[mt] = *(const short8*)(Ahi + a);
            al[mt] = *(const short8*)(Alo + a);
        }
        short8 bh[NT], bl[NT];
#pragma unroll
        for (int nt = 0; nt < NT; ++nt) {
            int t = wave * NT + nt;
            size_t fb = ((size_t)(t * KB + kb) * 64 + lane) * 8;
            bh[nt] = *(const short8*)(Whi + fb);
            bl[nt] = *(const short8*)(Wlo + fb);
        }
#pragma unroll
        for (int mt = 0; mt < 4; ++mt)
#pragma unroll
            for (int nt = 0; nt < NT; ++nt) {
                acc[mt][nt] = __builtin_amdgcn_mfma_f32_16x16x32_bf16(ah[mt], bh[nt], acc[mt][nt], 0, 0, 0);
                acc[mt][nt] = __builtin_amdgcn_mfma_f32_16x16x32_bf16(ah[mt], bl[nt], acc[mt][nt], 0, 0, 0);
                acc[mt][nt] = __builtin_amdgcn_mfma_f32_16x16x32_bf16(al[mt], bh[nt], acc[mt][nt], 0, 0, 0);
            }
    }

#pragma unroll
    for (int mt = 0; mt < 4; ++mt) {
#pragma unroll
        for (int nt = 0; nt < NT; ++nt) {
            int col = wave * (NT * 16) + nt * 16 + lane15;
            float bj = BIAS ? b[col] : 0.f;
#pragma unroll
            for (int reg = 0; reg < 4; ++reg) {
                int row = row0 + mt * 16 + quad * 4 + reg;
                if (row < n) {
                    float v = acc[mt][nt][reg] + bj;
                    if (RELU) v = fmaxf(v, 0.f);
                    if (SCALE) v *= sc[row];
                    if (OMODE == 1) {
                        O16[(size_t)row * D + col] = f2b(v);
                    } else {
                        short h, l;
                        bf16split(v, h, l);
                        Ohi[(size_t)row * D + col] = (unsigned short)h;
                        Olo[(size_t)row * D + col] = (unsigned short)l;
                    }
                }
            }
        }
    }
}

// ---------------- readout: one block per graph, atomic-free mean ----------------
__global__ void graph_mean(const int* __restrict__ bstart, const float* __restrict__ X,
                           float* __restrict__ out) {
    int g = blockIdx.x;
    int r0 = bstart[g], r1 = bstart[g + 1];
    int col = threadIdx.x & 127, rr = threadIdx.x >> 7;
    float acc = 0.f;
    for (int r = r0 + rr; r < r1; r += 2)
        acc += X[(size_t)r * OUT_D + col];
    __shared__ float sh[128];
    if (rr == 1) sh[col] = acc;
    __syncthreads();
    if (rr == 0) {
        float tot = acc + sh[col];
        int c = r1 - r0;
        out[(size_t)g * OUT_D + col] = tot / (float)(c > 0 ? c : 1);
    }
}

extern "C" void kernel_launch(void* const* d_in, const int* in_sizes, int n_in,
                              void* d_out, int out_size, void* d_ws, size_t ws_size,
                              hipStream_t stream) {
    const int* node_ids = (const int*)d_in[0];
    const int* edge_index = (const int*)d_in[1];
    const int* batch = (const int*)d_in[2];
    const float* embed = (const float*)d_in[3];
    const float* W_in  = (const float*)d_in[4];
    const float* b_in  = (const float*)d_in[5];
    const float* W_h1  = (const float*)d_in[6];
    const float* b_h1  = (const float*)d_in[7];
    const float* W_h2  = (const float*)d_in[8];
    const float* b_h2  = (const float*)d_in[9];
    const float* W_out = (const float*)d_in[10];
    const float* b_out = (const float*)d_in[11];
    float* out = (float*)d_out;

    const int* src = edge_index;
    const int* dst = edge_index + N_EDGES;

    char* w = (char*)d_ws;
    size_t o = 0;
    auto alloc = [&](size_t bytes) -> void* {
        void* p = w + o;
        o = (o + bytes + 255) & ~(size_t)255;
        return p;
    };
    int*   deg8     = (int*)alloc((size_t)NSHARD * N_NODES * sizeof(int));
    int*   sb8      = (int*)alloc((size_t)NSHARD * N_NODES * sizeof(int));
    int*   degt     = (int*)alloc((size_t)N_NODES * sizeof(int));
    int*   pos      = (int*)alloc((size_t)N_EDGES * sizeof(int));
    float* dinv     = (float*)alloc((size_t)N_NODES * sizeof(float));
    int*   bstart   = (int*)alloc((size_t)(NGRAPH + 1) * sizeof(int));
    int*   row_start= (int*)alloc((size_t)(N_NODES + 1) * sizeof(int));
    int*   bsum     = (int*)alloc((size_t)SCAN_B * sizeof(int));
    int*   boff     = (int*)alloc((size_t)SCAN_B * sizeof(int));
    int*   csr_src  = (int*)alloc((size_t)N_EDGES * sizeof(int));
    unsigned short* Xhi = (unsigned short*)alloc((size_t)N_PAD * HID_D * sizeof(short));
    unsigned short* Xlo = (unsigned short*)alloc((size_t)N_PAD * HID_D * sizeof(short));
    unsigned short* H16 = (unsigned short*)alloc((size_t)N_NODES * HID_D * sizeof(short));
    unsigned short* A1hi = (unsigned short*)alloc((size_t)N_PAD * 128 * sizeof(short));
    unsigned short* A1lo = (unsigned short*)alloc((size_t)N_PAD * 128 * sizeof(short));
    float* A1f      = (float*)alloc((size_t)N_NODES * 128 * sizeof(float));
    short* Whi_in   = (short*)alloc((size_t)EMB_D * HID_D * sizeof(short));
    short* Wlo_in   = (short*)alloc((size_t)EMB_D * HID_D * sizeof(short));
    short* Whi_h1   = (short*)alloc((size_t)HID_D * HID_D * sizeof(short));
    short* Wlo_h1   = (short*)alloc((size_t)HID_D * HID_D * sizeof(short));
    short* Whi_h2   = (short*)alloc((size_t)HID_D * HID_D * sizeof(short));
    short* Wlo_h2   = (short*)alloc((size_t)HID_D * HID_D * sizeof(short));
    short* Whi_out  = (short*)alloc((size_t)HID_D * OUT_D * sizeof(short));
    short* Wlo_out  = (short*)alloc((size_t)HID_D * OUT_D * sizeof(short));
    unsigned short* E16 = H16;               // layer-1 bf16 embeddings alias
    unsigned short* H4  = H16;               // layer-4 bf16 GEMM out [N,128] alias
    (void)ws_size;

    hipMemsetAsync(deg8, 0, (size_t)NSHARD * N_NODES * sizeof(int), stream);

    rank_kernel<<<(N_EDGES + 255) / 256, 256, 0, stream>>>(dst, deg8, pos);
    bstart_kernel<<<1, 512, 0, stream>>>(batch, bstart);
    scan_a<<<SCAN_B, 256, 0, stream>>>(deg8, degt, sb8, bsum, dinv);
    scan_b<<<1, 256, 0, stream>>>(bsum, boff);
    scan_c<<<SCAN_B, 256, 0, stream>>>(degt, boff, row_start);
    scatter_kernel<<<(N_EDGES + 255) / 256, 256, 0, stream>>>(src, dst, pos, row_start,
                                                              sb8, csr_src);

    wsplit_k<EMB_D, HID_D><<<(EMB_D * HID_D + 255) / 256, 256, 0, stream>>>(W_in, Whi_in, Wlo_in);
    wsplit_k<HID_D, HID_D><<<(HID_D * HID_D + 255) / 256, 256, 0, stream>>>(W_h1, Whi_h1, Wlo_h1);
    wsplit_k<HID_D, HID_D><<<(HID_D * HID_D + 255) / 256, 256, 0, stream>>>(W_h2, Whi_h2, Wlo_h2);
    wsplit_k<HID_D, OUT_D><<<(HID_D * OUT_D + 255) / 256, 256, 0, stream>>>(W_out, Whi_out, Wlo_out);

    const int gemm_grid = (N_NODES + 63) / 64;
    const int agg_grid = (N_NODES + 3) / 4;

    // ---- Layer 1: gather emb (pre-scaled bf16), agg at 128 (split out), GEMM 128->256 ----
    gather_bf16<<<(N_NODES * (EMB_D / 4) + 255) / 256, 256, 0, stream>>>(node_ids, embed, dinv, E16);
    agg_node<128, false, false, false, 2><<<agg_grid, 256, 0, stream>>>(
        row_start, csr_src, dinv, E16, nullptr, nullptr, A1hi, A1lo);
    gemm_direct<128, 256, true, true, 2, false><<<gemm_grid, 256, 0, stream>>>(
        A1hi, A1lo, Whi_in, Wlo_in, b_in, nullptr, nullptr, Xhi, Xlo, N_NODES);

    // ---- Layer 2: GEMM 256->256 (row-scaled bf16 out), agg (split out, res from X planes) ----
    gemm_direct<256, 256, false, false, 1, true><<<gemm_grid, 256, 0, stream>>>(
        Xhi, Xlo, Whi_h1, Wlo_h1, nullptr, dinv, H16, nullptr, nullptr, N_NODES);
    agg_node<256, true, true, true, 2><<<agg_grid, 256, 0, stream>>>(
        row_start, csr_src, dinv, H16, b_h1, nullptr, Xhi, Xlo);

    // ---- Layer 3: same ----
    gemm_direct<256, 256, false, false, 1, true><<<gemm_grid, 256, 0, stream>>>(
        Xhi, Xlo, Whi_h2, Wlo_h2, nullptr, dinv, H16, nullptr, nullptr, N_NODES);
    agg_node<256, true, true, true, 2><<<agg_grid, 256, 0, stream>>>(
        row_start, csr_src, dinv, H16, b_h2, nullptr, Xhi, Xlo);

    // ---- Layer 4: GEMM 256->128 (row-scaled bf16 out), agg at 128 +bias (fp32 out) ----
    gemm_direct<256, 128, false, false, 1, true><<<gemm_grid, 256, 0, stream>>>(
        Xhi, Xlo, Whi_out, Wlo_out, nullptr, dinv, H4, nullptr, nullptr, N_NODES);
    agg_node<128, true, false, false, 0><<<agg_grid, 256, 0, stream>>>(
        row_start, csr_src, dinv, H4, b_out, A1f, nullptr, nullptr);

    // ---- readout ----
    graph_mean<<<NGRAPH, 256, 0, stream>>>(bstart, A1f, out);
}